// Round 13
// baseline (883.472 us; speedup 1.0000x reference)
//
#include <hip/hip_runtime.h>
#include <math.h>

#define NN 100000
#define NE 800000
#define NH 128
#define NC 40
#define NB_SCAN 98   // ceil(NN/1024)
#define LDH 136      // LDS row stride in shorts (272 B): 16B-aligned, 2-way bank alias only

typedef __attribute__((ext_vector_type(8))) short short8;
typedef __attribute__((ext_vector_type(4))) float floatx4;

__device__ __forceinline__ unsigned short f2b(float f) {
  union { float f; unsigned int u; } x; x.f = f;
  unsigned int r = x.u + 0x7fff + ((x.u >> 16) & 1);  // RTNE
  return (unsigned short)(r >> 16);
}
__device__ __forceinline__ float b2f(unsigned int h16) {  // low 16 bits
  union { unsigned int u; float f; } x; x.u = h16 << 16;
  return x.f;
}
__device__ __forceinline__ unsigned int pk(float lo, float hi) {
  return (unsigned int)f2b(lo) | ((unsigned int)f2b(hi) << 16);
}
__device__ __forceinline__ void acc8(float* a, float w, uint4 v) {
  a[0] = fmaf(w, b2f(v.x & 0xffff), a[0]); a[1] = fmaf(w, b2f(v.x >> 16), a[1]);
  a[2] = fmaf(w, b2f(v.y & 0xffff), a[2]); a[3] = fmaf(w, b2f(v.y >> 16), a[3]);
  a[4] = fmaf(w, b2f(v.z & 0xffff), a[4]); a[5] = fmaf(w, b2f(v.z >> 16), a[5]);
  a[6] = fmaf(w, b2f(v.w & 0xffff), a[6]); a[7] = fmaf(w, b2f(v.w >> 16), a[7]);
}

// compact 4 B edge meta: low 17 bits = src (<2^17), high 15 bits = weight fp32 bits[31:17]
__device__ __forceinline__ void gather_node(const uint4* __restrict__ H4,
                                            const unsigned int* __restrict__ em,
                                            int e0, int e1, int csub, float* a) {
  float c1[8] = {0,0,0,0,0,0,0,0};
  float c2[8] = {0,0,0,0,0,0,0,0};
  float c3[8] = {0,0,0,0,0,0,0,0};
  int e = e0;
  for (; e + 4 <= e1; e += 4) {
    unsigned int m0 = em[e], m1 = em[e + 1], m2 = em[e + 2], m3 = em[e + 3];
    uint4 v0 = H4[(size_t)(m0 & 0x1FFFFu) * 16 + csub];
    uint4 v1 = H4[(size_t)(m1 & 0x1FFFFu) * 16 + csub];
    uint4 v2 = H4[(size_t)(m2 & 0x1FFFFu) * 16 + csub];
    uint4 v3 = H4[(size_t)(m3 & 0x1FFFFu) * 16 + csub];
    acc8(a,  __uint_as_float(m0 & 0xFFFE0000u), v0);
    acc8(c1, __uint_as_float(m1 & 0xFFFE0000u), v1);
    acc8(c2, __uint_as_float(m2 & 0xFFFE0000u), v2);
    acc8(c3, __uint_as_float(m3 & 0xFFFE0000u), v3);
  }
  for (; e < e1; ++e) {
    unsigned int m0 = em[e];
    uint4 v0 = H4[(size_t)(m0 & 0x1FFFFu) * 16 + csub];
    acc8(a, __uint_as_float(m0 & 0xFFFE0000u), v0);
  }
#pragma unroll
  for (int i = 0; i < 8; ++i) a[i] = (a[i] + c1[i]) + (c2[i] + c3[i]);
}

// ---------------- merged prep: hist + xconv + wconv + w10conv (all independent) ----------------
#define HIST_B   3125   // NE/256
#define XCONV_B 12500   // NN*NH/4 / 256
#define WCONV_B   576   // 9*16384 / 256
#define W10_B      32   // 64*128 / 256
#define PREP_GRID (HIST_B + XCONV_B + WCONV_B + W10_B)

__global__ __launch_bounds__(256) void prep_kernel(const int* __restrict__ dst,
                                                   int* __restrict__ cnt,
                                                   const float* __restrict__ x,
                                                   unsigned short* __restrict__ xb,
                                                   const float* __restrict__ W1,
                                                   const float* __restrict__ Wh,
                                                   unsigned short* __restrict__ WT,
                                                   const float* __restrict__ W10,
                                                   unsigned short* __restrict__ W10b) {
  int bid = blockIdx.x, tid = threadIdx.x;
  if (bid < HIST_B) {
    int i = bid * 256 + tid;
    if (i < NE) atomicAdd(&cnt[dst[i]], 1);
  } else if (bid < HIST_B + XCONV_B) {
    int i = (bid - HIST_B) * 256 + tid;  // exact: 3.2M float4
    float4 v = ((const float4*)x)[i];
    uint2 o; o.x = pk(v.x, v.y); o.y = pk(v.z, v.w);
    ((uint2*)xb)[i] = o;
  } else if (bid < HIST_B + XCONV_B + WCONV_B) {
    int idx = (bid - HIST_B - XCONV_B) * 256 + tid;  // exact: 9*16384
    int l = idx >> 14, r = idx & 16383;
    int k = r >> 7, n = r & 127;
    const float* W = (l == 0) ? W1 : (Wh + (size_t)(l - 1) * 16384);
    WT[(size_t)l * 16384 + n * 128 + k] = f2b(W[r]);
  } else {
    int idx = (bid - HIST_B - XCONV_B - WCONV_B) * 256 + tid;  // exact: 64*128
    int n = idx >> 7, k = idx & 127;
    W10b[idx] = (n < NC) ? f2b(W10[k * NC + n]) : (unsigned short)0;
  }
}

// ---------------- CSR scan + scatter ----------------
__global__ __launch_bounds__(1024) void scan1_kernel(const int* __restrict__ cnt,
                                                     int* __restrict__ rp,
                                                     int* __restrict__ bsum, int n) {
  __shared__ int buf[1024];
  int t = threadIdx.x, i = blockIdx.x * 1024 + t;
  int v = (i < n) ? cnt[i] : 0;
  buf[t] = v;
  __syncthreads();
  for (int off = 1; off < 1024; off <<= 1) {
    int x = (t >= off) ? buf[t - off] : 0;
    __syncthreads();
    buf[t] += x;
    __syncthreads();
  }
  if (i < n) rp[i] = buf[t] - v;
  if (t == 1023) bsum[blockIdx.x] = buf[t];
}

__global__ __launch_bounds__(128) void scan2_kernel(const int* __restrict__ bsum,
                                                    int* __restrict__ boff, int nb) {
  __shared__ int buf[128];
  int t = threadIdx.x;
  int v = (t < nb) ? bsum[t] : 0;
  buf[t] = v;
  __syncthreads();
  for (int off = 1; off < 128; off <<= 1) {
    int x = (t >= off) ? buf[t - off] : 0;
    __syncthreads();
    buf[t] += x;
    __syncthreads();
  }
  if (t < nb) boff[t] = buf[t] - v;
  if (t == 127) boff[nb] = buf[t];
}

__global__ void scan3_kernel(int* __restrict__ rp, int* __restrict__ roff,
                             const int* __restrict__ boff, int n, int nb) {
  int i = blockIdx.x * 256 + threadIdx.x;
  if (i < n) {
    int v = rp[i] + boff[i >> 10];
    rp[i] = v;
    roff[i] = v;
  }
  if (i == 0) rp[n] = boff[nb];
}

__global__ void scatter_kernel(const int* __restrict__ src, const int* __restrict__ dst,
                               const float* __restrict__ ew, int* __restrict__ off,
                               unsigned int* __restrict__ em, int E) {
  int i = blockIdx.x * 256 + threadIdx.x;
  if (i < E) {
    int p = atomicAdd(&off[dst[i]], 1);
    em[p] = (__float_as_uint(ew[i]) & 0xFFFE0000u) | (unsigned int)src[i];
  }
}

// ---------------- fused layer: Hout = bf16(relu((A*Hin)*W + b) [+ Hin]) ----------------
// 64 rows/block. Phase 1: gather agg rows into LDS + stage residual rows (coalesced).
// Phase 2: 32x64 MFMA quadrant per wave; B-fragments from global WT (L2-hot).
// Hout stores are NONTEMPORAL: table is cold-read next layer; stop L2/L3 write-allocate.
__global__ __launch_bounds__(256, 4) void layer_kernel(const unsigned short* __restrict__ Hin,
                                                       const int* __restrict__ rp,
                                                       const unsigned int* __restrict__ em,
                                                       const unsigned short* __restrict__ WT,
                                                       const float* __restrict__ bias,
                                                       unsigned short* __restrict__ Hout,
                                                       int residual) {
  __shared__ unsigned short Hs[64 * LDH];
  __shared__ unsigned short Rs[64 * LDH];
  int tid = threadIdx.x;
  int wave = tid >> 6, lane = tid & 63;
  int row0 = blockIdx.x * 64;
  int nsub = lane >> 4;   // 0..3
  int csub = lane & 15;   // 0..15 -> cols csub*8 .. +7
  const uint4* H4 = (const uint4*)Hin;  // 16 uint4 per row

  for (int r = 0; r < 4; ++r) {
    int nl = r * 16 + wave * 4 + nsub;
    int node = row0 + nl;
    int cn = (node < NN) ? node : (NN - 1);
    uint4 rv = H4[(size_t)cn * 16 + csub];          // residual stage (coalesced)
    *(uint4*)(Rs + nl * LDH + csub * 8) = rv;
    float a[8] = {0,0,0,0,0,0,0,0};
    if (node < NN) gather_node(H4, em, rp[node], rp[node + 1], csub, a);
    uint4 o;
    o.x = pk(a[0], a[1]);
    o.y = pk(a[2], a[3]);
    o.z = pk(a[4], a[5]);
    o.w = pk(a[6], a[7]);
    *(uint4*)(Hs + nl * LDH + csub * 8) = o;
  }
  __syncthreads();

  int m = lane & 15;
  int quad = lane >> 4;
  int wr0 = (wave >> 1) * 32;   // 2 m-tiles per wave
  int wc0 = (wave & 1) * 64;    // 4 n-tiles per wave

  floatx4 acc[2][4];
#pragma unroll
  for (int mt = 0; mt < 2; ++mt)
#pragma unroll
    for (int nt = 0; nt < 4; ++nt) acc[mt][nt] = (floatx4){0.f, 0.f, 0.f, 0.f};

#pragma unroll
  for (int ks = 0; ks < 4; ++ks) {
    short8 af[2], bf[4];
#pragma unroll
    for (int mt = 0; mt < 2; ++mt)
      af[mt] = *(const short8*)(Hs + (wr0 + mt * 16 + m) * LDH + quad * 8 + ks * 32);
#pragma unroll
    for (int nt = 0; nt < 4; ++nt)
      bf[nt] = *(const short8*)(WT + (size_t)(wc0 + nt * 16 + m) * 128 + quad * 8 + ks * 32);
#pragma unroll
    for (int mt = 0; mt < 2; ++mt)
#pragma unroll
      for (int nt = 0; nt < 4; ++nt)
        acc[mt][nt] = __builtin_amdgcn_mfma_f32_16x16x32_bf16(af[mt], bf[nt], acc[mt][nt], 0, 0, 0);
  }

  // D: row = quad*4+reg (within 16-tile), col = wc0 + nt*16 + m
#pragma unroll
  for (int nt = 0; nt < 4; ++nt) {
    int col = wc0 + nt * 16 + m;
    float bcol = bias[col];
#pragma unroll
    for (int mt = 0; mt < 2; ++mt) {
#pragma unroll
      for (int reg = 0; reg < 4; ++reg) {
        int lr = wr0 + mt * 16 + quad * 4 + reg;   // local row
        int gr = row0 + lr;
        if (gr < NN) {
          float v = fmaxf(acc[mt][nt][reg] + bcol, 0.f);
          if (residual) v += b2f(Rs[lr * LDH + col]);
          __builtin_nontemporal_store(f2b(v), &Hout[(size_t)gr * 128 + col]);
        }
      }
    }
  }
}

// ---------------- fused final: out = log_softmax(relu((A*Hin)*W10 + b10)) ----------------
__global__ __launch_bounds__(256, 4) void final_kernel(const unsigned short* __restrict__ Hin,
                                                       const int* __restrict__ rp,
                                                       const unsigned int* __restrict__ em,
                                                       const unsigned short* __restrict__ W10b,
                                                       const float* __restrict__ b10,
                                                       float* __restrict__ out) {
  __shared__ unsigned short Hs[64 * LDH];
  int tid = threadIdx.x;
  int wave = tid >> 6, lane = tid & 63;
  int row0 = blockIdx.x * 64;
  int nsub = lane >> 4;
  int csub = lane & 15;
  const uint4* H4 = (const uint4*)Hin;

  for (int r = 0; r < 4; ++r) {
    int nl = r * 16 + wave * 4 + nsub;
    int node = row0 + nl;
    float a[8] = {0,0,0,0,0,0,0,0};
    if (node < NN) gather_node(H4, em, rp[node], rp[node + 1], csub, a);
    uint4 o;
    o.x = pk(a[0], a[1]);
    o.y = pk(a[2], a[3]);
    o.z = pk(a[4], a[5]);
    o.w = pk(a[6], a[7]);
    *(uint4*)(Hs + nl * LDH + csub * 8) = o;
  }
  __syncthreads();

  int m = lane & 15;
  int quad = lane >> 4;

  floatx4 acc[4];
#pragma unroll
  for (int nt = 0; nt < 4; ++nt) acc[nt] = (floatx4){0.f, 0.f, 0.f, 0.f};

#pragma unroll
  for (int ks = 0; ks < 4; ++ks) {
    short8 af = *(const short8*)(Hs + (wave * 16 + m) * LDH + quad * 8 + ks * 32);
#pragma unroll
    for (int nt = 0; nt < 4; ++nt) {
      short8 bf = *(const short8*)(W10b + (size_t)(nt * 16 + m) * 128 + quad * 8 + ks * 32);
      acc[nt] = __builtin_amdgcn_mfma_f32_16x16x32_bf16(af, bf, acc[nt], 0, 0, 0);
    }
  }

  // D: row = wave*16 + quad*4 + reg, col = nt*16 + m. Valid cols < 40.
  float b0 = b10[m];
  float b1 = b10[16 + m];
  float b2v = (m < 8) ? b10[32 + m] : 0.f;
#pragma unroll
  for (int reg = 0; reg < 4; ++reg) {
    int gr = row0 + wave * 16 + quad * 4 + reg;
    float l0 = fmaxf(acc[0][reg] + b0, 0.f);
    float l1 = fmaxf(acc[1][reg] + b1, 0.f);
    float l2 = (m < 8) ? fmaxf(acc[2][reg] + b2v, 0.f) : -INFINITY;
    float mx = fmaxf(fmaxf(l0, l1), l2);
#pragma unroll
    for (int msk = 1; msk < 16; msk <<= 1) mx = fmaxf(mx, __shfl_xor(mx, msk));
    float ss = expf(l0 - mx) + expf(l1 - mx) + ((m < 8) ? expf(l2 - mx) : 0.f);
#pragma unroll
    for (int msk = 1; msk < 16; msk <<= 1) ss += __shfl_xor(ss, msk);
    float lse = mx + logf(ss);
    if (gr < NN) {
      out[(size_t)gr * NC + m] = l0 - lse;
      out[(size_t)gr * NC + 16 + m] = l1 - lse;
      if (m < 8) out[(size_t)gr * NC + 32 + m] = l2 - lse;
    }
  }
}

extern "C" void kernel_launch(void* const* d_in, const int* in_sizes, int n_in,
                              void* d_out, int out_size, void* d_ws, size_t ws_size,
                              hipStream_t stream) {
  const float* x   = (const float*)d_in[0];
  const int*   src = (const int*)d_in[1];
  const int*   dst = (const int*)d_in[2];
  const float* ew  = (const float*)d_in[3];
  const float* W1  = (const float*)d_in[4];
  const float* Wh  = (const float*)d_in[5];
  const float* W10 = (const float*)d_in[6];
  const float* b1  = (const float*)d_in[7];
  const float* bh  = (const float*)d_in[8];
  const float* b10 = (const float*)d_in[9];
  float* out = (float*)d_out;

  // workspace layout (256B-aligned chunks), ~60 MB
  char* p = (char*)d_ws;
  int*   rp    = (int*)p;            p += (((size_t)(NN + 1) * 4 + 255) / 256) * 256;
  int*   roff  = (int*)p;            p += (((size_t)NN * 4 + 255) / 256) * 256;
  int*   bsum  = (int*)p;            p += 256 * 4;
  int*   boff  = (int*)p;            p += 256 * 4;
  unsigned int* em = (unsigned int*)p; p += (size_t)NE * 4;
  unsigned short* hA   = (unsigned short*)p; p += (size_t)NN * NH * 2;
  unsigned short* hB   = (unsigned short*)p; p += (size_t)NN * NH * 2;  // also x-bf16
  unsigned short* WT   = (unsigned short*)p; p += (size_t)9 * NH * NH * 2;
  unsigned short* W10b = (unsigned short*)p; p += (size_t)64 * NH * 2;

  // ---- merged prep (hist + x->bf16 + W->bf16^T + W10->bf16 padded) ----
  hipMemsetAsync(roff, 0, (size_t)NN * 4, stream);
  prep_kernel<<<PREP_GRID, 256, 0, stream>>>(dst, roff, x, hB, W1, Wh, WT, W10, W10b);

  // ---- CSR scan + scatter ----
  scan1_kernel<<<NB_SCAN, 1024, 0, stream>>>(roff, rp, bsum, NN);
  scan2_kernel<<<1, 128, 0, stream>>>(bsum, boff, NB_SCAN);
  scan3_kernel<<<(NN + 255) / 256, 256, 0, stream>>>(rp, roff, boff, NN, NB_SCAN);
  scatter_kernel<<<(NE + 255) / 256, 256, 0, stream>>>(src, dst, ew, roff, em, NE);

  int layer_grid = (NN + 63) / 64;

  // ---- layer 1: hA = relu((A*x)W1 + b1) ----
  layer_kernel<<<layer_grid, 256, 0, stream>>>(hB, rp, em, WT, b1, hA, 0);

  // ---- 8 hidden residual layers (ping-pong hA/hB) ----
  unsigned short* cur = hA;
  unsigned short* nxt = hB;
  for (int i = 0; i < 8; ++i) {
    layer_kernel<<<layer_grid, 256, 0, stream>>>(
        cur, rp, em, WT + (size_t)(i + 1) * NH * NH, bh + (size_t)i * NH, nxt, 1);
    unsigned short* t = cur; cur = nxt; nxt = t;
  }
  // after 8 swaps, cur == hA

  // ---- fused final layer + log_softmax ----
  final_kernel<<<layer_grid, 256, 0, stream>>>(cur, rp, em, W10b, b10, out);
}